// Round 1
// baseline (487.694 us; speedup 1.0000x reference)
//
#include <hip/hip_runtime.h>
#include <math.h>

#define NSP 4096   // H*W
#define CC  128    // channels
#define CIC 64     // inter channels
#define NB  4      // batch

// workspace float offsets
#define WS_P     0
#define WS_Y     (NB * 192 * NSP)             // 3,145,728
#define WS_STATS (WS_Y + NB * CIC * NSP)      // 4,194,304

// -------------------- Kernel 1: fused 1x1 projections (g, theta, phi) ----------
// grid (NSP/64, NB), block 256. P[b][o][n], o: 0..63=g, 64..127=theta, 128..191=phi
__global__ __launch_bounds__(256) void proj_kernel(
    const float* __restrict__ x,
    const float* __restrict__ g_w, const float* __restrict__ g_b,
    const float* __restrict__ t_w, const float* __restrict__ t_b,
    const float* __restrict__ p_w, const float* __restrict__ p_b,
    float* __restrict__ P)
{
    __shared__ float Wt[CC][196];   // Wt[c][o] = W(o,c), padded (196 = 4 mod 32, 16B aligned)
    __shared__ float Xs[CC][68];    // x tile [c][n_local]

    const int b   = blockIdx.y;
    const int n0  = blockIdx.x * 64;
    const int tid = threadIdx.x;
    const int nl  = tid & 63;
    const int og  = tid >> 6;       // 0..3
    const int ob  = og * 48;        // this wave's output-channel base

    // stage all 3 weight matrices transposed into LDS (coalesced global reads)
    for (int j = 0; j < 32; ++j) {
        int idx = tid + (j << 8);          // 0..8191
        int o = idx >> 7, c = idx & 127;
        Wt[c][o]       = g_w[idx];
        Wt[c][64 + o]  = t_w[idx];
        Wt[c][128 + o] = p_w[idx];
    }
    // stage x tile via float4
    const float* xb = x + (size_t)b * CC * NSP + n0;
    for (int k = 0; k < 8; ++k) {
        int fi = tid + (k << 8);           // 0..2047 float4s
        int c = fi >> 4, q = (fi & 15) << 2;
        *(float4*)&Xs[c][q] = *(const float4*)(xb + (size_t)c * NSP + q);
    }
    __syncthreads();

    float acc[48];
    #pragma unroll
    for (int j = 0; j < 48; ++j) {
        int o = ob + j;
        acc[j] = (o < 64) ? g_b[o] : (o < 128) ? t_b[o - 64] : p_b[o - 128];
    }

    for (int c = 0; c < CC; ++c) {
        float xv = Xs[c][nl];
        const float4* wr = (const float4*)&Wt[c][ob];
        #pragma unroll
        for (int j4 = 0; j4 < 12; ++j4) {
            float4 w4 = wr[j4];
            acc[j4 * 4 + 0] += w4.x * xv;
            acc[j4 * 4 + 1] += w4.y * xv;
            acc[j4 * 4 + 2] += w4.z * xv;
            acc[j4 * 4 + 3] += w4.w * xv;
        }
    }

    float* Pb = P + (size_t)b * 192 * NSP + n0 + nl;
    #pragma unroll
    for (int j = 0; j < 48; ++j)
        Pb[(size_t)(ob + j) * NSP] = acc[j];
}

// -------------------- Kernel 2: flash attention over spatial tokens ------------
// grid (NSP/64, NB), block 512 (8 waves). Each block: 64 queries, loop K/V tiles of 64.
// thread: r = query row (lane), grp = wave -> owns 8 ci outputs and computes 8 mj scores.
__global__ __launch_bounds__(512) void attn_kernel(
    const float* __restrict__ P, float* __restrict__ y)
{
    __shared__ float Qs[CIC][68];   // theta[ci][r]
    __shared__ float Ks[CIC][68];   // phi[ci][mj]
    __shared__ float Vs[CIC][68];   // g[ci][mj]
    __shared__ float Sp[64][65];    // scores, then p-values (stride 65: conflict-free col reads)
    __shared__ float Pm[8][65];     // per-wave partial row maxes

    const int b   = blockIdx.y;
    const int q0  = blockIdx.x * 64;
    const int tid = threadIdx.x;
    const int r   = tid & 63;
    const int grp = tid >> 6;       // 0..7
    const int c0  = grp << 3;       // ci base (PV) and mj base (scores)

    const float* Pg = P + (size_t)b * 192 * NSP;        // g rows
    const float* Pt = Pg + (size_t)CIC * NSP;           // theta rows
    const float* Pp = Pt + (size_t)CIC * NSP;           // phi rows

    // load Q tile (64x64) via float4
    for (int k = 0; k < 2; ++k) {
        int fi = tid + (k << 9);            // 0..1023
        int ci = fi >> 4, q = (fi & 15) << 2;
        *(float4*)&Qs[ci][q] = *(const float4*)(Pt + (size_t)ci * NSP + q0 + q);
    }

    float O[8];
    #pragma unroll
    for (int k = 0; k < 8; ++k) O[k] = 0.f;
    float m_run = -1e30f, l_run = 0.f;

    for (int t = 0; t < 64; ++t) {
        const int m0 = t * 64;
        __syncthreads();   // A: previous PV reads of Sp/Vs complete
        for (int k = 0; k < 2; ++k) {
            int fi = tid + (k << 9);
            int ci = fi >> 4, q = (fi & 15) << 2;
            *(float4*)&Ks[ci][q] = *(const float4*)(Pp + (size_t)ci * NSP + m0 + q);
            *(float4*)&Vs[ci][q] = *(const float4*)(Pg + (size_t)ci * NSP + m0 + q);
        }
        __syncthreads();   // B: K/V (and Q on first iter) visible

        // scores: S[r][c0..c0+7]
        float sv[8] = {0.f,0.f,0.f,0.f,0.f,0.f,0.f,0.f};
        #pragma unroll 4
        for (int ci = 0; ci < CIC; ++ci) {
            float qv = Qs[ci][r];
            float4 k0 = *(const float4*)&Ks[ci][c0];
            float4 k1 = *(const float4*)&Ks[ci][c0 + 4];
            sv[0] += qv * k0.x; sv[1] += qv * k0.y;
            sv[2] += qv * k0.z; sv[3] += qv * k0.w;
            sv[4] += qv * k1.x; sv[5] += qv * k1.y;
            sv[6] += qv * k1.z; sv[7] += qv * k1.w;
        }
        // per-thread partial max -> LDS
        float pm = sv[0];
        #pragma unroll
        for (int k = 1; k < 8; ++k) pm = fmaxf(pm, sv[k]);
        Pm[grp][r] = pm;
        __syncthreads();   // C: partial maxes visible

        float tmax = Pm[0][r];
        #pragma unroll
        for (int g = 1; g < 8; ++g) tmax = fmaxf(tmax, Pm[g][r]);
        float m_new = fmaxf(m_run, tmax);
        float scale = __expf(m_run - m_new);

        // exp own entries, write p back into Sp
        #pragma unroll
        for (int k = 0; k < 8; ++k)
            Sp[r][c0 + k] = __expf(sv[k] - m_new);
        __syncthreads();   // E: p-values visible

        // PV: O[k] += sum_mj p[r][mj] * Vs[c0+k][mj]
        #pragma unroll
        for (int k = 0; k < 8; ++k) O[k] *= scale;
        float lt = 0.f;
        for (int mj = 0; mj < 64; ++mj) {
            float pv = Sp[r][mj];
            lt += pv;
            #pragma unroll
            for (int k = 0; k < 8; ++k)
                O[k] += pv * Vs[c0 + k][mj];
        }
        l_run = l_run * scale + lt;
        m_run = m_new;
    }

    float inv = 1.0f / l_run;
    float* yb = y + (size_t)b * CIC * NSP + q0 + r;
    #pragma unroll
    for (int k = 0; k < 8; ++k)
        yb[(size_t)(c0 + k) * NSP] = O[k] * inv;
}

// -------------------- Kernel 3: W 1x1 conv -> w_y into d_out --------------------
// grid (NSP/64, NB), block 256. out[b][c][n] = w_b[c] + sum_ci w_w[c][ci]*y[b][ci][n]
__global__ __launch_bounds__(256) void wconv_kernel(
    const float* __restrict__ y, const float* __restrict__ w_w,
    const float* __restrict__ w_b, float* __restrict__ out)
{
    __shared__ float WsT[CIC][132];  // WsT[ci][c] = w_w[c][ci]
    __shared__ float Ys[CIC][68];

    const int b   = blockIdx.y;
    const int n0  = blockIdx.x * 64;
    const int tid = threadIdx.x;
    const int nl  = tid & 63;
    const int grp = tid >> 6;       // 0..3
    const int c0  = grp * 32;

    for (int j = 0; j < 32; ++j) {
        int idx = tid + (j << 8);           // 0..8191
        int c = idx >> 6, ci = idx & 63;
        WsT[ci][c] = w_w[idx];
    }
    for (int k = 0; k < 4; ++k) {
        int fi = tid + (k << 8);            // 0..1023 float4s
        int ci = fi >> 4, q = (fi & 15) << 2;
        *(float4*)&Ys[ci][q] = *(const float4*)(y + ((size_t)b * CIC + ci) * NSP + n0 + q);
    }
    __syncthreads();

    float acc[32];
    #pragma unroll
    for (int j = 0; j < 32; ++j) acc[j] = 0.f;

    for (int ci = 0; ci < CIC; ++ci) {
        float yv = Ys[ci][nl];
        const float4* wr = (const float4*)&WsT[ci][c0];
        #pragma unroll
        for (int j4 = 0; j4 < 8; ++j4) {
            float4 w4 = wr[j4];
            acc[j4 * 4 + 0] += w4.x * yv;
            acc[j4 * 4 + 1] += w4.y * yv;
            acc[j4 * 4 + 2] += w4.z * yv;
            acc[j4 * 4 + 3] += w4.w * yv;
        }
    }

    #pragma unroll
    for (int j = 0; j < 32; ++j)
        out[((size_t)b * CC + c0 + j) * NSP + n0 + nl] = acc[j] + w_b[c0 + j];
}

// -------------------- Kernel 4: per-channel batch stats -------------------------
// grid (CC), block 256. stats[c]=mean, stats[CC+c]=1/sqrt(var+eps)
__global__ __launch_bounds__(256) void stats_kernel(
    const float* __restrict__ wy, float* __restrict__ stats)
{
    const int c   = blockIdx.x;
    const int tid = threadIdx.x;
    double s = 0.0, ss = 0.0;
    for (int i = tid; i < NB * NSP; i += 256) {
        int b = i >> 12, n = i & (NSP - 1);
        float v = wy[((size_t)b * CC + c) * NSP + n];
        s += v; ss += (double)v * v;
    }
    #pragma unroll
    for (int off = 32; off > 0; off >>= 1) {
        s  += __shfl_down(s, off);
        ss += __shfl_down(ss, off);
    }
    __shared__ double sred[4], ssred[4];
    const int wid = tid >> 6, lane = tid & 63;
    if (lane == 0) { sred[wid] = s; ssred[wid] = ss; }
    __syncthreads();
    if (tid == 0) {
        double st  = sred[0] + sred[1] + sred[2] + sred[3];
        double sst = ssred[0] + ssred[1] + ssred[2] + ssred[3];
        double mean = st / 16384.0;
        double var  = sst / 16384.0 - mean * mean;
        stats[c]      = (float)mean;
        stats[CC + c] = (float)(1.0 / sqrt(var + 1e-5));
    }
}

// -------------------- Kernel 5: BN + residual (in-place on d_out) ---------------
// grid 2048, block 256: one float4 per thread, exact cover of 2,097,152 floats
__global__ __launch_bounds__(256) void bn_kernel(
    const float* __restrict__ x, const float* __restrict__ stats,
    const float* __restrict__ gamma, const float* __restrict__ beta,
    float* __restrict__ out)
{
    const int i = blockIdx.x * 256 + threadIdx.x;   // float4 index
    const int c = (i >> 10) & (CC - 1);             // 1024 float4 per (b,c)
    float mean = stats[c];
    float istd = stats[CC + c];
    float ga = gamma[c] * istd;
    float be = beta[c] - mean * ga;
    float4 wy = ((const float4*)out)[i];
    float4 xv = ((const float4*)x)[i];
    float4 o;
    o.x = wy.x * ga + be + xv.x;
    o.y = wy.y * ga + be + xv.y;
    o.z = wy.z * ga + be + xv.z;
    o.w = wy.w * ga + be + xv.w;
    ((float4*)out)[i] = o;
}

extern "C" void kernel_launch(void* const* d_in, const int* in_sizes, int n_in,
                              void* d_out, int out_size, void* d_ws, size_t ws_size,
                              hipStream_t stream)
{
    const float* x    = (const float*)d_in[0];
    const float* g_w  = (const float*)d_in[1];
    const float* g_b  = (const float*)d_in[2];
    const float* t_w  = (const float*)d_in[3];
    const float* t_b  = (const float*)d_in[4];
    const float* p_w  = (const float*)d_in[5];
    const float* p_b  = (const float*)d_in[6];
    const float* w_w  = (const float*)d_in[7];
    const float* w_b  = (const float*)d_in[8];
    const float* bn_g = (const float*)d_in[9];
    const float* bn_b = (const float*)d_in[10];
    float* out = (float*)d_out;
    float* ws  = (float*)d_ws;

    float* P     = ws + WS_P;       // [NB][192][NSP]
    float* y     = ws + WS_Y;       // [NB][CIC][NSP]
    float* stats = ws + WS_STATS;   // [2][CC]

    proj_kernel <<<dim3(NSP / 64, NB), 256, 0, stream>>>(x, g_w, g_b, t_w, t_b, p_w, p_b, P);
    attn_kernel <<<dim3(NSP / 64, NB), 512, 0, stream>>>(P, y);
    wconv_kernel<<<dim3(NSP / 64, NB), 256, 0, stream>>>(y, w_w, w_b, out);
    stats_kernel<<<dim3(CC), 256, 0, stream>>>(out, stats);
    bn_kernel   <<<dim3(2048), 256, 0, stream>>>(x, stats, bn_g, bn_b, out);
}

// Round 2
// 189.742 us; speedup vs baseline: 2.5703x; 2.5703x over previous
//
#include <hip/hip_runtime.h>
#include <math.h>

#define NSP 4096   // H*W
#define CC  128    // channels
#define CIC 64     // inter channels
#define NB  4      // batch

typedef unsigned short u16;
typedef short s8bf __attribute__((ext_vector_type(8)));
typedef float f32x4 __attribute__((ext_vector_type(4)));

#define MFMA(a, b, c) __builtin_amdgcn_mfma_f32_16x16x32_bf16(a, b, c, 0, 0, 0)

// workspace byte offsets
#define WSB_PB    0                         // bf16 [B][192][NSP]  (g:0-63, theta:64-127, phi:128-191)
#define WSB_PH    (NB * 192 * NSP * 2)      // bf16 [B][NSP][64]   phi token-major
#define WSB_Y     (WSB_PH + NB * NSP * CIC * 2)   // f32 [B][64][NSP]
#define WSB_STATS (WSB_Y + NB * CIC * NSP * 4)    // f32 [2][128]

__device__ __forceinline__ u16 f2bf(float f) {
    union { float f; unsigned u; } v; v.f = f;
    unsigned r = v.u + 0x7fffu + ((v.u >> 16) & 1u);
    return (u16)(r >> 16);
}

// -------------------- Kernel 1: fused 1x1 projections -> bf16 channel-major ----
__global__ __launch_bounds__(256) void proj_kernel(
    const float* __restrict__ x,
    const float* __restrict__ g_w, const float* __restrict__ g_b,
    const float* __restrict__ t_w, const float* __restrict__ t_b,
    const float* __restrict__ p_w, const float* __restrict__ p_b,
    u16* __restrict__ PB)
{
    __shared__ float Wt[CC][196];
    __shared__ float Xs[CC][68];

    const int b   = blockIdx.y;
    const int n0  = blockIdx.x * 64;
    const int tid = threadIdx.x;
    const int nl  = tid & 63;
    const int og  = tid >> 6;
    const int ob  = og * 48;

    for (int j = 0; j < 32; ++j) {
        int idx = tid + (j << 8);
        int o = idx >> 7, c = idx & 127;
        Wt[c][o]       = g_w[idx];
        Wt[c][64 + o]  = t_w[idx];
        Wt[c][128 + o] = p_w[idx];
    }
    const float* xb = x + (size_t)b * CC * NSP + n0;
    for (int k = 0; k < 8; ++k) {
        int fi = tid + (k << 8);
        int c = fi >> 4, q = (fi & 15) << 2;
        *(float4*)&Xs[c][q] = *(const float4*)(xb + (size_t)c * NSP + q);
    }
    __syncthreads();

    float acc[48];
    #pragma unroll
    for (int j = 0; j < 48; ++j) {
        int o = ob + j;
        acc[j] = (o < 64) ? g_b[o] : (o < 128) ? t_b[o - 64] : p_b[o - 128];
    }

    for (int c = 0; c < CC; ++c) {
        float xv = Xs[c][nl];
        const float4* wr = (const float4*)&Wt[c][ob];
        #pragma unroll
        for (int j4 = 0; j4 < 12; ++j4) {
            float4 w4 = wr[j4];
            acc[j4 * 4 + 0] += w4.x * xv;
            acc[j4 * 4 + 1] += w4.y * xv;
            acc[j4 * 4 + 2] += w4.z * xv;
            acc[j4 * 4 + 3] += w4.w * xv;
        }
    }

    u16* Pb = PB + (size_t)b * 192 * NSP + n0 + nl;
    #pragma unroll
    for (int j = 0; j < 48; ++j)
        Pb[(size_t)(ob + j) * NSP] = f2bf(acc[j]);
}

// -------------------- Kernel 2: transpose phi cm -> tm (bf16) ------------------
__global__ __launch_bounds__(256) void trph_kernel(
    const u16* __restrict__ PB, u16* __restrict__ ph_tm)
{
    __shared__ u16 T[64][72];
    const int b = blockIdx.y, n0 = blockIdx.x * 64, tid = threadIdx.x;
    const u16* src = PB + ((size_t)b * 192 + 128) * NSP + n0;
    for (int k = 0; k < 4; ++k) {
        int fi = tid + (k << 8);
        int ci = fi >> 4, q = (fi & 15) << 2;
        *(ushort4*)&T[ci][q] = *(const ushort4*)(src + (size_t)ci * NSP + q);
    }
    __syncthreads();
    u16* dst = ph_tm + ((size_t)b * NSP + n0) * 64;
    for (int k = 0; k < 4; ++k) {
        int fi = tid + (k << 8);
        int t = fi >> 4, c4 = (fi & 15) << 2;
        ushort4 v;
        v.x = T[c4][t]; v.y = T[c4 + 1][t]; v.z = T[c4 + 2][t]; v.w = T[c4 + 3][t];
        *(ushort4*)(dst + (size_t)t * 64 + c4) = v;
    }
}

// -------------------- Kernel 3: MFMA flash attention ---------------------------
// block = 256 thr = 4 waves: wave w -> strip s=w&1 (q rows q0+16s..+16), KV half hh=w>>1.
// grid (NSP/32, NB). Online softmax per lane (rows 4*g16+reg), merge halves via LDS.
__global__ __launch_bounds__(256) void attn_kernel(
    const u16* __restrict__ PB, const u16* __restrict__ ph_tm,
    float* __restrict__ y)
{
    const int b    = blockIdx.y;
    const int q0   = blockIdx.x << 5;
    const int tid  = threadIdx.x;
    const int lane = tid & 63;
    const int w    = tid >> 6;
    const int s    = w & 1;
    const int hh   = w >> 1;
    const int l15  = lane & 15;
    const int g16  = lane >> 4;

    __shared__ __align__(16) u16 Plds[4][16][72];
    __shared__ float Om[2][16][69];
    __shared__ float Mm[2][16], Lm[2][16];

    const u16* gp  = PB + (size_t)b * 192 * NSP;          // g  cm [64][NSP]
    const u16* thc = gp + (size_t)CIC * NSP;              // theta cm [64][NSP]
    const u16* php = ph_tm + (size_t)b * NSP * 64;        // phi tm [NSP][64]

    // Q fragments: gather 16 scalars from channel-major theta (once)
    s8bf qa0, qa1;
    const int qtok = q0 + s * 16 + l15;
    #pragma unroll
    for (int j = 0; j < 8; ++j) {
        qa0[j] = (short)thc[(size_t)(g16 * 8 + j) * NSP + qtok];
        qa1[j] = (short)thc[(size_t)(32 + g16 * 8 + j) * NSP + qtok];
    }

    f32x4 Ov[4];
    float mr[4], lr[4];
    #pragma unroll
    for (int c = 0; c < 4; ++c) Ov[c] = (f32x4){0.f, 0.f, 0.f, 0.f};
    #pragma unroll
    for (int r = 0; r < 4; ++r) { mr[r] = -1e30f; lr[r] = 0.f; }

    for (int t = 0; t < 32; ++t) {
        const int mb = (hh * 32 + t) * 64;

        // ---- QK^T: S strip 16x64 ----
        f32x4 sv[4];
        const u16* kb = php + ((size_t)(mb + l15) << 6) + (g16 << 3);
        #pragma unroll
        for (int c = 0; c < 4; ++c) {
            sv[c] = (f32x4){0.f, 0.f, 0.f, 0.f};
            s8bf k0 = *(const s8bf*)(kb + (c << 10));
            s8bf k1 = *(const s8bf*)(kb + (c << 10) + 32);
            sv[c] = MFMA(qa0, k0, sv[c]);
            sv[c] = MFMA(qa1, k1, sv[c]);
        }

        // ---- online softmax ----
        float pm[4];
        #pragma unroll
        for (int r = 0; r < 4; ++r)
            pm[r] = fmaxf(fmaxf(sv[0][r], sv[1][r]), fmaxf(sv[2][r], sv[3][r]));
        #pragma unroll
        for (int msk = 1; msk <= 8; msk <<= 1) {
            #pragma unroll
            for (int r = 0; r < 4; ++r)
                pm[r] = fmaxf(pm[r], __shfl_xor(pm[r], msk, 64));
        }
        float esc[4], ls[4];
        #pragma unroll
        for (int r = 0; r < 4; ++r) {
            float mn = fmaxf(mr[r], pm[r]);
            esc[r] = __expf(mr[r] - mn);
            mr[r] = mn;
            ls[r] = 0.f;
        }
        #pragma unroll
        for (int c = 0; c < 4; ++c) {
            #pragma unroll
            for (int r = 0; r < 4; ++r) {
                float p = __expf(sv[c][r] - mr[r]);
                ls[r] += p;
                Plds[w][g16 * 4 + r][c * 16 + l15] = f2bf(p);
            }
        }
        #pragma unroll
        for (int msk = 1; msk <= 8; msk <<= 1) {
            #pragma unroll
            for (int r = 0; r < 4; ++r)
                ls[r] += __shfl_xor(ls[r], msk, 64);
        }
        #pragma unroll
        for (int r = 0; r < 4; ++r)
            lr[r] = lr[r] * esc[r] + ls[r];
        #pragma unroll
        for (int c = 0; c < 4; ++c) {
            #pragma unroll
            for (int r = 0; r < 4; ++r)
                Ov[c][r] *= esc[r];
        }

        // ---- PV: O strip 16x64 ----
        s8bf pa0 = *(const s8bf*)&Plds[w][l15][g16 * 8];
        s8bf pa1 = *(const s8bf*)&Plds[w][l15][32 + g16 * 8];
        const u16* vb = gp + (size_t)l15 * NSP + mb + (g16 << 3);
        #pragma unroll
        for (int c = 0; c < 4; ++c) {
            s8bf v0 = *(const s8bf*)(vb + ((size_t)c << 16));
            s8bf v1 = *(const s8bf*)(vb + ((size_t)c << 16) + 32);
            Ov[c] = MFMA(pa0, v0, Ov[c]);
            Ov[c] = MFMA(pa1, v1, Ov[c]);
        }
    }

    // ---- merge KV halves ----
    if (hh == 1) {
        #pragma unroll
        for (int c = 0; c < 4; ++c) {
            #pragma unroll
            for (int r = 0; r < 4; ++r)
                Om[s][g16 * 4 + r][c * 16 + l15] = Ov[c][r];
        }
        if (l15 == 0) {
            #pragma unroll
            for (int r = 0; r < 4; ++r) { Mm[s][g16 * 4 + r] = mr[r]; Lm[s][g16 * 4 + r] = lr[r]; }
        }
    }
    __syncthreads();
    if (hh == 0) {
        float a1[4], a2[4];
        #pragma unroll
        for (int r = 0; r < 4; ++r) {
            int row = g16 * 4 + r;
            float m2 = Mm[s][row], l2 = Lm[s][row];
            float ms = fmaxf(mr[r], m2);
            float e1 = __expf(mr[r] - ms), e2 = __expf(m2 - ms);
            float inv = 1.0f / (lr[r] * e1 + l2 * e2);
            a1[r] = e1 * inv; a2[r] = e2 * inv;
        }
        #pragma unroll
        for (int c = 0; c < 4; ++c) {
            #pragma unroll
            for (int r = 0; r < 4; ++r) {
                int row = g16 * 4 + r, col = c * 16 + l15;
                Om[s][row][col] = Ov[c][r] * a1[r] + Om[s][row][col] * a2[r];
            }
        }
    }
    __syncthreads();

    // ---- coalesced y write: [64 ci][32 q] block region ----
    #pragma unroll
    for (int k = 0; k < 2; ++k) {
        int fi = tid + (k << 8);
        int ci = fi >> 3, qo = (fi & 7) << 2;
        int st = qo >> 4, r0 = qo & 15;
        float4 v;
        v.x = Om[st][r0][ci]; v.y = Om[st][r0 + 1][ci];
        v.z = Om[st][r0 + 2][ci]; v.w = Om[st][r0 + 3][ci];
        *(float4*)&y[((size_t)b * CIC + ci) * NSP + q0 + qo] = v;
    }
}

// -------------------- Kernel 4: W 1x1 conv -> w_y into d_out --------------------
__global__ __launch_bounds__(256) void wconv_kernel(
    const float* __restrict__ y, const float* __restrict__ w_w,
    const float* __restrict__ w_b, float* __restrict__ out)
{
    __shared__ float WsT[CIC][132];
    __shared__ float Ys[CIC][68];

    const int b   = blockIdx.y;
    const int n0  = blockIdx.x * 64;
    const int tid = threadIdx.x;
    const int nl  = tid & 63;
    const int grp = tid >> 6;
    const int c0  = grp * 32;

    for (int j = 0; j < 32; ++j) {
        int idx = tid + (j << 8);
        int c = idx >> 6, ci = idx & 63;
        WsT[ci][c] = w_w[idx];
    }
    for (int k = 0; k < 4; ++k) {
        int fi = tid + (k << 8);
        int ci = fi >> 4, q = (fi & 15) << 2;
        *(float4*)&Ys[ci][q] = *(const float4*)(y + ((size_t)b * CIC + ci) * NSP + n0 + q);
    }
    __syncthreads();

    float acc[32];
    #pragma unroll
    for (int j = 0; j < 32; ++j) acc[j] = 0.f;

    for (int ci = 0; ci < CIC; ++ci) {
        float yv = Ys[ci][nl];
        const float4* wr = (const float4*)&WsT[ci][c0];
        #pragma unroll
        for (int j4 = 0; j4 < 8; ++j4) {
            float4 w4 = wr[j4];
            acc[j4 * 4 + 0] += w4.x * yv;
            acc[j4 * 4 + 1] += w4.y * yv;
            acc[j4 * 4 + 2] += w4.z * yv;
            acc[j4 * 4 + 3] += w4.w * yv;
        }
    }

    #pragma unroll
    for (int j = 0; j < 32; ++j)
        out[((size_t)b * CC + c0 + j) * NSP + n0 + nl] = acc[j] + w_b[c0 + j];
}

// -------------------- Kernel 5: per-channel batch stats -------------------------
__global__ __launch_bounds__(256) void stats_kernel(
    const float* __restrict__ wy, float* __restrict__ stats)
{
    const int c   = blockIdx.x;
    const int tid = threadIdx.x;
    double s = 0.0, ss = 0.0;
    for (int i = tid; i < NB * NSP; i += 256) {
        int b = i >> 12, n = i & (NSP - 1);
        float v = wy[((size_t)b * CC + c) * NSP + n];
        s += v; ss += (double)v * v;
    }
    #pragma unroll
    for (int off = 32; off > 0; off >>= 1) {
        s  += __shfl_down(s, off);
        ss += __shfl_down(ss, off);
    }
    __shared__ double sred[4], ssred[4];
    const int wid = tid >> 6, lane = tid & 63;
    if (lane == 0) { sred[wid] = s; ssred[wid] = ss; }
    __syncthreads();
    if (tid == 0) {
        double st  = sred[0] + sred[1] + sred[2] + sred[3];
        double sst = ssred[0] + ssred[1] + ssred[2] + ssred[3];
        double mean = st / 16384.0;
        double var  = sst / 16384.0 - mean * mean;
        stats[c]      = (float)mean;
        stats[CC + c] = (float)(1.0 / sqrt(var + 1e-5));
    }
}

// -------------------- Kernel 6: BN + residual (in-place on d_out) ---------------
__global__ __launch_bounds__(256) void bn_kernel(
    const float* __restrict__ x, const float* __restrict__ stats,
    const float* __restrict__ gamma, const float* __restrict__ beta,
    float* __restrict__ out)
{
    const int i = blockIdx.x * 256 + threadIdx.x;
    const int c = (i >> 10) & (CC - 1);
    float mean = stats[c];
    float istd = stats[CC + c];
    float ga = gamma[c] * istd;
    float be = beta[c] - mean * ga;
    float4 wy = ((const float4*)out)[i];
    float4 xv = ((const float4*)x)[i];
    float4 o;
    o.x = wy.x * ga + be + xv.x;
    o.y = wy.y * ga + be + xv.y;
    o.z = wy.z * ga + be + xv.z;
    o.w = wy.w * ga + be + xv.w;
    ((float4*)out)[i] = o;
}

extern "C" void kernel_launch(void* const* d_in, const int* in_sizes, int n_in,
                              void* d_out, int out_size, void* d_ws, size_t ws_size,
                              hipStream_t stream)
{
    const float* x    = (const float*)d_in[0];
    const float* g_w  = (const float*)d_in[1];
    const float* g_b  = (const float*)d_in[2];
    const float* t_w  = (const float*)d_in[3];
    const float* t_b  = (const float*)d_in[4];
    const float* p_w  = (const float*)d_in[5];
    const float* p_b  = (const float*)d_in[6];
    const float* w_w  = (const float*)d_in[7];
    const float* w_b  = (const float*)d_in[8];
    const float* bn_g = (const float*)d_in[9];
    const float* bn_b = (const float*)d_in[10];
    float* out = (float*)d_out;
    char* ws8  = (char*)d_ws;

    u16*   PB    = (u16*)(ws8 + WSB_PB);
    u16*   PH    = (u16*)(ws8 + WSB_PH);
    float* y     = (float*)(ws8 + WSB_Y);
    float* stats = (float*)(ws8 + WSB_STATS);

    proj_kernel <<<dim3(NSP / 64, NB), 256, 0, stream>>>(x, g_w, g_b, t_w, t_b, p_w, p_b, PB);
    trph_kernel <<<dim3(NSP / 64, NB), 256, 0, stream>>>(PB, PH);
    attn_kernel <<<dim3(NSP / 32, NB), 256, 0, stream>>>(PB, PH, y);
    wconv_kernel<<<dim3(NSP / 64, NB), 256, 0, stream>>>(y, w_w, w_b, out);
    stats_kernel<<<dim3(CC), 256, 0, stream>>>(out, stats);
    bn_kernel   <<<dim3(2048), 256, 0, stream>>>(x, stats, bn_g, bn_b, out);
}